// Round 8
// baseline (400.088 us; speedup 1.0000x reference)
//
#include <hip/hip_runtime.h>
#include <hip/hip_bf16.h>
#include <cstdint>

typedef unsigned short ushort_t;
typedef unsigned int uint_t;
typedef __bf16 bf16x8 __attribute__((ext_vector_type(8)));
typedef float f32x4 __attribute__((ext_vector_type(4)));

#define B_SZ 32
#define C_IN 256
#define C_OUT 256
#define H_SZ 56
#define W_SZ 56
#define HW 3136          // 56*56
#define HP 58            // padded H (halo 1 each side)
#define WP 58            // padded W
#define BN_EPS 1e-5f
#define K_ZERO 128       // channels zeroed per batch; 128 survive
#define NPX 7168         // prep_x role blocks: 4 cit * 56 h * 32 b

__device__ __forceinline__ ushort_t f2bf(float f) {
    unsigned int u = __builtin_bit_cast(unsigned int, f);
    unsigned int r = (u + 0x7fffu + ((u >> 16) & 1u)) >> 16;
    return (ushort_t)r;
}

__device__ __forceinline__ void load_lds16(const void* gptr, void* ldsptr) {
    __builtin_amdgcn_global_load_lds(
        (const __attribute__((address_space(1))) unsigned int*)(uintptr_t)gptr,
        (__attribute__((address_space(3))) unsigned int*)(uintptr_t)ldsptr,
        16, 0, 0);
}

// ---------------------------------------------------------------------------
// Kernel 1 (MERGED prep): blocks [0,7168) do prep_x (x NCHW fp32 -> padded
// NHWC bf16 + per-(b,h) abs-mean partials, no atomics). Blocks [7168,7424)
// do prep_w (coalesced LDS-staged transpose to Wt[tap][co][ci] + BN consts).
// ---------------------------------------------------------------------------
__global__ __launch_bounds__(256) void prep_kernel(const float* __restrict__ x,
                                                   const float* __restrict__ w,
                                                   const float* __restrict__ gamma,
                                                   const float* __restrict__ beta,
                                                   const float* __restrict__ mean,
                                                   const float* __restrict__ var,
                                                   ushort_t* __restrict__ Wt,
                                                   float* __restrict__ bninv,
                                                   float* __restrict__ bnadd,
                                                   float* __restrict__ s_part,
                                                   ushort_t* __restrict__ xbp) {
    const int bx = blockIdx.x, t = threadIdx.x;
    __shared__ __align__(16) char smem[15616];   // max(tile 14592+red2 1024, wl 9216)

    if (bx >= NPX) {
        // ---- prep_w role: one block per co ----
        const int co = bx - NPX;
        float* wl = (float*)smem;   // 2304 floats
        const float4* src4 = (const float4*)(w + (size_t)co * 2304);
        for (int i = t; i < 576; i += 256) ((float4*)wl)[i] = src4[i];
        if (co == 32) {
            float inv = gamma[t] * rsqrtf(var[t] + BN_EPS);
            bninv[t] = inv;
            bnadd[t] = beta[t] - mean[t] * inv;
        }
        __syncthreads();
        for (int i = t; i < 2304; i += 256) {
            int tap = i >> 8, ci = i & 255;
            Wt[tap * (C_OUT * C_IN) + co * C_IN + ci] = f2bf(wl[ci * 9 + tap]);
        }
        return;
    }

    // ---- prep_x role: bx = (b*56+h)*4 + cit ----
    const int cit = bx & 3;
    const int hb = bx >> 2;        // b*56 + h
    const int h = hb % 56;
    const int b = hb / 56;
    float (*tile)[57] = (float (*)[57])smem;         // 64 x 57 fp32
    float* red2 = (float*)(smem + 14592);            // 256 fp32
    const float* src = x + ((size_t)(b * C_IN + cit * 64) * H_SZ + h) * W_SZ;
    for (int i = t; i < 64 * 14; i += 256) {
        int ci = i / 14, w4 = (i - ci * 14) * 4;
        float4 v = *(const float4*)(src + (size_t)ci * HW + w4);
        tile[ci][w4] = v.x; tile[ci][w4 + 1] = v.y;
        tile[ci][w4 + 2] = v.z; tile[ci][w4 + 3] = v.w;
    }
    __syncthreads();
    {
        int ci = t & 63, wg = t >> 6;
        float a = 0.f;
#pragma unroll
        for (int j = 0; j < 14; j++) a += fabsf(tile[ci][wg * 14 + j]);
        red2[t] = a;
    }
    __syncthreads();
    if (t < 64) {
        float tot = red2[t] + red2[t + 64] + red2[t + 128] + red2[t + 192];
        s_part[(size_t)hb * C_IN + cit * 64 + t] = tot * (1.0f / (float)HW);
    }
    const uint2 z2 = make_uint2(0u, 0u);
    for (int i = t; i < W_SZ * 8; i += 256) {
        int w_ = i >> 3, c8 = (i & 7) * 8;
        uint4 v;
        v.x = (uint_t)f2bf(tile[c8][w_])     | ((uint_t)f2bf(tile[c8 + 1][w_]) << 16);
        v.y = (uint_t)f2bf(tile[c8 + 2][w_]) | ((uint_t)f2bf(tile[c8 + 3][w_]) << 16);
        v.z = (uint_t)f2bf(tile[c8 + 4][w_]) | ((uint_t)f2bf(tile[c8 + 5][w_]) << 16);
        v.w = (uint_t)f2bf(tile[c8 + 6][w_]) | ((uint_t)f2bf(tile[c8 + 7][w_]) << 16);
        size_t dst = ((size_t)((b * HP + h + 1) * WP + (w_ + 1))) * C_IN + cit * 64 + c8;
        *(uint4*)&xbp[dst] = v;
    }
    if (t < 32) {
        int side = t >> 4, c4 = (t & 15) * 4;
        size_t dst = ((size_t)((b * HP + h + 1) * WP + side * 57)) * C_IN + cit * 64 + c4;
        *(uint2*)&xbp[dst] = z2;
    }
    if (h == 0 || h == 55) {
        int prow = (h == 0) ? 0 : 57;
        for (int i = t; i < 58 * 16; i += 256) {
            int w_ = i >> 4, c4 = (i & 15) * 4;
            size_t dst = ((size_t)((b * HP + prow) * WP + w_)) * C_IN + cit * 64 + c4;
            *(uint2*)&xbp[dst] = z2;
        }
    }
}

// ---------------------------------------------------------------------------
// Kernel 2: gate -> per-batch channel permutation + compacted scales.
// ---------------------------------------------------------------------------
__global__ __launch_bounds__(256) void gate_kernel(const float* __restrict__ s_part,
                                                   const float* __restrict__ gw,
                                                   const float* __restrict__ gb,
                                                   ushort_t* __restrict__ perm,
                                                   float* __restrict__ cscale) {
    const int b = blockIdx.x, t = threadIdx.x;
    __shared__ float sh_s[C_IN], sh_g[C_OUT], red[256];
    {
        const float* sp = s_part + (size_t)b * 56 * C_IN + t;
        float v = 0.f;
#pragma unroll 8
        for (int h = 0; h < 56; h++) v += sp[(size_t)h * C_IN];
        sh_s[t] = v;
    }
    __syncthreads();
    float acc = gb[t];
    const float4* s4 = (const float4*)sh_s;
    const float4* w4 = (const float4*)(gw + (size_t)t * C_IN);
    for (int ci = 0; ci < C_IN / 4; ci++) {
        float4 a = s4[ci], wv = w4[ci];
        acc += a.x * wv.x + a.y * wv.y + a.z * wv.z + a.w * wv.w;
    }
    float g = fmaxf(acc, 0.f);
    sh_g[t] = g;
    __syncthreads();
    int cnt = 0;
    for (int j = 0; j < C_OUT; j++) {
        float gj = sh_g[j];
        cnt += (gj < g) || (gj == g && j < t);
    }
    float tv = (cnt >= K_ZERO) ? g : 0.f;
    red[t] = tv;
    __syncthreads();
    for (int off = 128; off > 0; off >>= 1) {
        if (t < off) red[t] += red[t + off];
        __syncthreads();
    }
    if (cnt >= K_ZERO) {
        int pos = cnt - K_ZERO;
        perm[b * C_OUT + pos] = (ushort_t)t;
        cscale[b * K_ZERO + pos] = tv * ((float)C_OUT / red[0]);
    } else {
        perm[b * C_OUT + K_ZERO + cnt] = (ushort_t)t;
    }
}

// ---------------------------------------------------------------------------
// Kernel 3: implicit-GEMM conv, B-IN-REGISTERS edition.
// Diagnosis r7: CU LDS pipe is ~half of conv time (12 waves x 16 ds_read_b128
// + 8 load_lds-writes per stage ~ 3000 cyc x 36 stages). B-fragments are
// lane-private gathers of L2-resident Wt -> load them straight to VGPRs
// (8 x global_load_dwordx4/lane/stage, issued before barrier-1 so the
// existing drain covers them; each wave touches exactly 64 aligned 128 B
// lines/stage). Removes the whole B LDS path (-4 lds-writes, -8 ds_reads
// per thread/stage), LDS 32->16 KB. Byte-identical operands: old LDS read
// gave global chunk c = (lane>>4)+ks*4 of row rb; new load reads
// Wt[tap][coK[nt]][cq*64 + c*8 ..+8] directly. A path / barriers /
// epilogue / swizzle unchanged (r2-verified).
// ---------------------------------------------------------------------------
__global__ __launch_bounds__(256, 3) void conv_kernel(const ushort_t* __restrict__ xbp,
                                                      const ushort_t* __restrict__ Wt,
                                                      const float* __restrict__ bninv,
                                                      const float* __restrict__ bnadd,
                                                      const ushort_t* __restrict__ perm,
                                                      const float* __restrict__ cscale,
                                                      float* __restrict__ out) {
    __shared__ __align__(16) ushort_t As[128 * 64];  // 16 KB (A only now)
    const int t = threadIdx.x;
    const int bxr = blockIdx.x;
    const int L = (bxr & 7) * 100 + (bxr >> 3);
    const int b = L / 25;          // 0..31, 4 consecutive batches per XCD
    const int tile = L - b * 25;   // 0..24 p-tiles within batch
    const int lane = t & 63;
    const int wv = t >> 6;
    const int waveM = wv >> 1, waveN = wv & 1;

    // A staging: chunk q = i*256+t -> row i*32+(t>>3), stored col t&7,
    // global col (t&7)^(row&7)
    const int srow = t >> 3;
    const int gxor8 = ((t & 7) ^ (srow & 7)) * 8;
    int arow[4];
#pragma unroll
    for (int i = 0; i < 4; i++) {
        int pl = tile * 128 + i * 32 + srow;
        pl = pl < HW ? pl : HW - 1;          // clamp tail tile inside batch
        int hh = pl / W_SZ, ww = pl - hh * W_SZ;
        arow[i] = ((b * HP + hh + 1) * WP + (ww + 1)) * C_IN + gxor8;
    }
    ushort_t* ldsA = As + t * 8;

    // A fragment LDS byte offsets: row r, global chunk c stored at c^(r&7)
    int aoff[2][4];
#pragma unroll
    for (int ks = 0; ks < 2; ks++) {
        int c = (lane >> 4) + ks * 4;
#pragma unroll
        for (int mt = 0; mt < 4; mt++) {
            int ra = waveM * 64 + mt * 16 + (lane & 15);
            aoff[ks][mt] = (ra * 8 + (c ^ (ra & 7))) * 16;
        }
    }

    // B per-lane global element offsets: row coK[nt] (perm gather, == the
    // epilogue's j-mapping), chunk (lane>>4) + ks*4 within the cq block.
    int coK[4], ebase[4];
#pragma unroll
    for (int nt = 0; nt < 4; nt++) {
        int j = waveN * 64 + nt * 16 + (lane & 15);
        coK[nt] = perm[b * C_OUT + j];
        ebase[nt] = coK[nt] * C_IN + (lane >> 4) * 8;
    }

    f32x4 acc[4][4];
#pragma unroll
    for (int i = 0; i < 4; i++)
#pragma unroll
        for (int j = 0; j < 4; j++) acc[i][j] = (f32x4){0.f, 0.f, 0.f, 0.f};

    const char* Ab = (const char*)As;

    for (int cq = 0; cq < 4; cq++) {
        const int ci0 = cq * 64;
        for (int tap = 0; tap < 9; tap++) {
            const int doff = ((tap / 3 - 1) * WP + (tap % 3 - 1)) * C_IN;
            const int woffe = tap * (C_OUT * C_IN) + ci0;
            // B -> registers (lane-private; drained by the barrier below)
            bf16x8 bfr[2][4];
#pragma unroll
            for (int ks = 0; ks < 2; ks++)
#pragma unroll
                for (int nt = 0; nt < 4; nt++)
                    bfr[ks][nt] = *(const bf16x8*)(Wt + woffe + ebase[nt] + ks * 32);
            // A -> LDS
#pragma unroll
            for (int i = 0; i < 4; i++)
                load_lds16(xbp + arow[i] + doff + ci0, ldsA + i * 2048);
            __syncthreads();
#pragma unroll
            for (int ks = 0; ks < 2; ks++) {
                bf16x8 af[4];
#pragma unroll
                for (int mt = 0; mt < 4; mt++) af[mt] = *(const bf16x8*)(Ab + aoff[ks][mt]);
#pragma unroll
                for (int mt = 0; mt < 4; mt++)
#pragma unroll
                    for (int nt = 0; nt < 4; nt++)
                        acc[mt][nt] = __builtin_amdgcn_mfma_f32_16x16x32_bf16(
                            af[mt], bfr[ks][nt], acc[mt][nt], 0, 0, 0);
            }
            __syncthreads();
        }
    }

    // epilogue: y = relu(acc*inv + add) * cscale, scatter to real channel;
    // plus zero-fill the dead channels over the same p rows.
    int coD[4];
    float invK[4], addK[4], tscK[4];
#pragma unroll
    for (int nt = 0; nt < 4; nt++) {
        int j = waveN * 64 + nt * 16 + (lane & 15);
        coD[nt] = perm[b * C_OUT + K_ZERO + j];
        invK[nt] = bninv[coK[nt]];
        addK[nt] = bnadd[coK[nt]];
        tscK[nt] = cscale[b * K_ZERO + j];
    }
    const float4 z4 = make_float4(0.f, 0.f, 0.f, 0.f);
#pragma unroll
    for (int mt = 0; mt < 4; mt++) {
        int pl0 = tile * 128 + waveM * 64 + mt * 16 + (lane >> 4) * 4;
        if (pl0 < HW) {
#pragma unroll
            for (int nt = 0; nt < 4; nt++) {
                float inv = invK[nt], add = addK[nt], tsc = tscK[nt];
                float4 o;
                o.x = fmaxf(acc[mt][nt][0] * inv + add, 0.f) * tsc;
                o.y = fmaxf(acc[mt][nt][1] * inv + add, 0.f) * tsc;
                o.z = fmaxf(acc[mt][nt][2] * inv + add, 0.f) * tsc;
                o.w = fmaxf(acc[mt][nt][3] * inv + add, 0.f) * tsc;
                *(float4*)(out + (size_t)(b * C_OUT + coK[nt]) * HW + pl0) = o;
                *(float4*)(out + (size_t)(b * C_OUT + coD[nt]) * HW + pl0) = z4;
            }
        }
    }
}

// ---------------------------------------------------------------------------
extern "C" void kernel_launch(void* const* d_in, const int* in_sizes, int n_in,
                              void* d_out, int out_size, void* d_ws, size_t ws_size,
                              hipStream_t stream) {
    const float* x      = (const float*)d_in[0];
    const float* conv_w = (const float*)d_in[1];
    const float* gate_w = (const float*)d_in[2];
    const float* gate_b = (const float*)d_in[3];
    const float* bn_g   = (const float*)d_in[4];
    const float* bn_b   = (const float*)d_in[5];
    const float* bn_m   = (const float*)d_in[6];
    const float* bn_v   = (const float*)d_in[7];
    float* out = (float*)d_out;

    char* ws = (char*)d_ws;
    float*    s_part = (float*)(ws + 0);          // 32*56*256 f32 = 1835008 B
    ushort_t* perm   = (ushort_t*)(ws + 1835008); // 32*256 u16 (16 KB)
    float*    cscale = (float*)(ws + 1851392);    // 32*128 f  (16 KB)
    float*    bninv  = (float*)(ws + 1867776);    // 256 f
    float*    bnadd  = (float*)(ws + 1868800);    // 256 f
    ushort_t* Wt     = (ushort_t*)(ws + 1869824); // 589824 bf16 (1179648 B)
    ushort_t* xbp    = (ushort_t*)(ws + 3049472); // 32*58*58*256 bf16

    prep_kernel<<<NPX + 256, 256, 0, stream>>>(x, conv_w, bn_g, bn_b, bn_m, bn_v,
                                               Wt, bninv, bnadd, s_part, xbp);
    gate_kernel<<<32, 256, 0, stream>>>(s_part, gate_w, gate_b, perm, cscale);
    conv_kernel<<<dim3(25 * 32), 256, 0, stream>>>(xbp, Wt, bninv, bnadd, perm, cscale, out);
}

// Round 9
// 336.646 us; speedup vs baseline: 1.1885x; 1.1885x over previous
//
#include <hip/hip_runtime.h>
#include <hip/hip_bf16.h>
#include <cstdint>

typedef unsigned short ushort_t;
typedef unsigned int uint_t;
typedef __bf16 bf16x8 __attribute__((ext_vector_type(8)));
typedef float f32x4 __attribute__((ext_vector_type(4)));

#define B_SZ 32
#define C_IN 256
#define C_OUT 256
#define H_SZ 56
#define W_SZ 56
#define HW 3136          // 56*56
#define HP 58            // padded H (halo 1 each side)
#define WP 58            // padded W
#define BN_EPS 1e-5f
#define K_ZERO 128       // channels zeroed per batch; 128 survive
#define NPX 7168         // prep_x role blocks: 4 cit * 56 h * 32 b

__device__ __forceinline__ ushort_t f2bf(float f) {
    unsigned int u = __builtin_bit_cast(unsigned int, f);
    unsigned int r = (u + 0x7fffu + ((u >> 16) & 1u)) >> 16;
    return (ushort_t)r;
}

__device__ __forceinline__ void load_lds16(const void* gptr, void* ldsptr) {
    __builtin_amdgcn_global_load_lds(
        (const __attribute__((address_space(1))) unsigned int*)(uintptr_t)gptr,
        (__attribute__((address_space(3))) unsigned int*)(uintptr_t)ldsptr,
        16, 0, 0);
}

// ---------------------------------------------------------------------------
// Kernel 1 (MERGED prep) -- ATTRIBUTION PROBE ROUND: the prep_x role runs
// its full load+convert+store work TWICE (rep loop, idempotent: pass 2
// rewrites identical bytes; x is L3-resident so both passes run at equal
// speed). Purpose: measure prep's true duration T via dur_us delta and
// (if 2T > ~99 us) a labeled top-5 entry. REVERT the rep loop next round.
// ---------------------------------------------------------------------------
__global__ __launch_bounds__(256) void prep_kernel(const float* __restrict__ x,
                                                   const float* __restrict__ w,
                                                   const float* __restrict__ gamma,
                                                   const float* __restrict__ beta,
                                                   const float* __restrict__ mean,
                                                   const float* __restrict__ var,
                                                   ushort_t* __restrict__ Wt,
                                                   float* __restrict__ bninv,
                                                   float* __restrict__ bnadd,
                                                   float* __restrict__ s_part,
                                                   ushort_t* __restrict__ xbp) {
    const int bx = blockIdx.x, t = threadIdx.x;
    __shared__ __align__(16) char smem[15616];   // max(tile 14592+red2 1024, wl 9216)

    if (bx >= NPX) {
        // ---- prep_w role: one block per co ----
        const int co = bx - NPX;
        float* wl = (float*)smem;   // 2304 floats
        const float4* src4 = (const float4*)(w + (size_t)co * 2304);
        for (int i = t; i < 576; i += 256) ((float4*)wl)[i] = src4[i];
        if (co == 32) {
            float inv = gamma[t] * rsqrtf(var[t] + BN_EPS);
            bninv[t] = inv;
            bnadd[t] = beta[t] - mean[t] * inv;
        }
        __syncthreads();
        for (int i = t; i < 2304; i += 256) {
            int tap = i >> 8, ci = i & 255;
            Wt[tap * (C_OUT * C_IN) + co * C_IN + ci] = f2bf(wl[ci * 9 + tap]);
        }
        return;
    }

    // ---- prep_x role: bx = (b*56+h)*4 + cit ----
    const int cit = bx & 3;
    const int hb = bx >> 2;        // b*56 + h
    const int h = hb % 56;
    const int b = hb / 56;
    float (*tile)[57] = (float (*)[57])smem;         // 64 x 57 fp32
    float* red2 = (float*)(smem + 14592);            // 256 fp32
    const float* src = x + ((size_t)(b * C_IN + cit * 64) * H_SZ + h) * W_SZ;

#pragma unroll 1
    for (int rep = 0; rep < 2; ++rep) {
        for (int i = t; i < 64 * 14; i += 256) {
            int ci = i / 14, w4 = (i - ci * 14) * 4;
            float4 v = *(const float4*)(src + (size_t)ci * HW + w4);
            tile[ci][w4] = v.x; tile[ci][w4 + 1] = v.y;
            tile[ci][w4 + 2] = v.z; tile[ci][w4 + 3] = v.w;
        }
        __syncthreads();
        {
            int ci = t & 63, wg = t >> 6;
            float a = 0.f;
#pragma unroll
            for (int j = 0; j < 14; j++) a += fabsf(tile[ci][wg * 14 + j]);
            red2[t] = a;
        }
        __syncthreads();
        if (t < 64) {
            float tot = red2[t] + red2[t + 64] + red2[t + 128] + red2[t + 192];
            s_part[(size_t)hb * C_IN + cit * 64 + t] = tot * (1.0f / (float)HW);
        }
        const uint2 z2 = make_uint2(0u, 0u);
        for (int i = t; i < W_SZ * 8; i += 256) {
            int w_ = i >> 3, c8 = (i & 7) * 8;
            uint4 v;
            v.x = (uint_t)f2bf(tile[c8][w_])     | ((uint_t)f2bf(tile[c8 + 1][w_]) << 16);
            v.y = (uint_t)f2bf(tile[c8 + 2][w_]) | ((uint_t)f2bf(tile[c8 + 3][w_]) << 16);
            v.z = (uint_t)f2bf(tile[c8 + 4][w_]) | ((uint_t)f2bf(tile[c8 + 5][w_]) << 16);
            v.w = (uint_t)f2bf(tile[c8 + 6][w_]) | ((uint_t)f2bf(tile[c8 + 7][w_]) << 16);
            size_t dst = ((size_t)((b * HP + h + 1) * WP + (w_ + 1))) * C_IN + cit * 64 + c8;
            *(uint4*)&xbp[dst] = v;
        }
        if (t < 32) {
            int side = t >> 4, c4 = (t & 15) * 4;
            size_t dst = ((size_t)((b * HP + h + 1) * WP + side * 57)) * C_IN + cit * 64 + c4;
            *(uint2*)&xbp[dst] = z2;
        }
        if (h == 0 || h == 55) {
            int prow = (h == 0) ? 0 : 57;
            for (int i = t; i < 58 * 16; i += 256) {
                int w_ = i >> 4, c4 = (i & 15) * 4;
                size_t dst = ((size_t)((b * HP + prow) * WP + w_)) * C_IN + cit * 64 + c4;
                *(uint2*)&xbp[dst] = z2;
            }
        }
        __syncthreads();   // protect tile/red2 before pass 2 overwrite
    }
}

// ---------------------------------------------------------------------------
// Kernel 2: gate -> per-batch channel permutation + compacted scales.
// VERBATIM r7.
// ---------------------------------------------------------------------------
__global__ __launch_bounds__(256) void gate_kernel(const float* __restrict__ s_part,
                                                   const float* __restrict__ gw,
                                                   const float* __restrict__ gb,
                                                   ushort_t* __restrict__ perm,
                                                   float* __restrict__ cscale) {
    const int b = blockIdx.x, t = threadIdx.x;
    __shared__ float sh_s[C_IN], sh_g[C_OUT], red[256];
    {
        const float* sp = s_part + (size_t)b * 56 * C_IN + t;
        float v = 0.f;
#pragma unroll 8
        for (int h = 0; h < 56; h++) v += sp[(size_t)h * C_IN];
        sh_s[t] = v;
    }
    __syncthreads();
    float acc = gb[t];
    const float4* s4 = (const float4*)sh_s;
    const float4* w4 = (const float4*)(gw + (size_t)t * C_IN);
    for (int ci = 0; ci < C_IN / 4; ci++) {
        float4 a = s4[ci], wv = w4[ci];
        acc += a.x * wv.x + a.y * wv.y + a.z * wv.z + a.w * wv.w;
    }
    float g = fmaxf(acc, 0.f);
    sh_g[t] = g;
    __syncthreads();
    int cnt = 0;
    for (int j = 0; j < C_OUT; j++) {
        float gj = sh_g[j];
        cnt += (gj < g) || (gj == g && j < t);
    }
    float tv = (cnt >= K_ZERO) ? g : 0.f;
    red[t] = tv;
    __syncthreads();
    for (int off = 128; off > 0; off >>= 1) {
        if (t < off) red[t] += red[t + off];
        __syncthreads();
    }
    if (cnt >= K_ZERO) {
        int pos = cnt - K_ZERO;
        perm[b * C_OUT + pos] = (ushort_t)t;
        cscale[b * K_ZERO + pos] = tv * ((float)C_OUT / red[0]);
    } else {
        perm[b * C_OUT + K_ZERO + cnt] = (ushort_t)t;
    }
}

// ---------------------------------------------------------------------------
// Kernel 3: implicit-GEMM conv + BN + ReLU over SURVIVING channels only.
// VERBATIM r2/r6/r7-verified version (99-100 us, FETCH 35 MB, MfmaUtil 25%).
// B-in-registers (r8) REFUTED: per-lane gathers + vmcnt serialization cost
// +85 us; async global_load_lds DMA + drain is the right structure here.
// ---------------------------------------------------------------------------
__global__ __launch_bounds__(256, 3) void conv_kernel(const ushort_t* __restrict__ xbp,
                                                      const ushort_t* __restrict__ Wt,
                                                      const float* __restrict__ bninv,
                                                      const float* __restrict__ bnadd,
                                                      const ushort_t* __restrict__ perm,
                                                      const float* __restrict__ cscale,
                                                      float* __restrict__ out) {
    __shared__ __align__(16) ushort_t As[128 * 64];  // 16 KB
    __shared__ __align__(16) ushort_t Bs[128 * 64];  // 16 KB
    const int t = threadIdx.x;
    const int bxr = blockIdx.x;
    const int L = (bxr & 7) * 100 + (bxr >> 3);
    const int b = L / 25;          // 0..31, 4 consecutive batches per XCD
    const int tile = L - b * 25;   // 0..24 p-tiles within batch
    const int lane = t & 63;
    const int wv = t >> 6;
    const int waveM = wv >> 1, waveN = wv & 1;

    const int srow = t >> 3;
    const int gxor8 = ((t & 7) ^ (srow & 7)) * 8;
    int arow[4], wrow[4];
#pragma unroll
    for (int i = 0; i < 4; i++) {
        int pl = tile * 128 + i * 32 + srow;
        pl = pl < HW ? pl : HW - 1;          // clamp tail tile inside batch
        int hh = pl / W_SZ, ww = pl - hh * W_SZ;
        arow[i] = ((b * HP + hh + 1) * WP + (ww + 1)) * C_IN + gxor8;
        int co = perm[b * C_OUT + i * 32 + srow];  // surviving channel gather
        wrow[i] = co * C_IN + gxor8;
    }
    ushort_t* ldsA = As + t * 8;
    ushort_t* ldsB = Bs + t * 8;

    int aoff[2][4], boff[2][4];
#pragma unroll
    for (int ks = 0; ks < 2; ks++) {
        int c = (lane >> 4) + ks * 4;
#pragma unroll
        for (int mt = 0; mt < 4; mt++) {
            int ra = waveM * 64 + mt * 16 + (lane & 15);
            aoff[ks][mt] = (ra * 8 + (c ^ (ra & 7))) * 16;
            int rb = waveN * 64 + mt * 16 + (lane & 15);
            boff[ks][mt] = (rb * 8 + (c ^ (rb & 7))) * 16;
        }
    }

    f32x4 acc[4][4];
#pragma unroll
    for (int i = 0; i < 4; i++)
#pragma unroll
        for (int j = 0; j < 4; j++) acc[i][j] = (f32x4){0.f, 0.f, 0.f, 0.f};

    const char* Ab = (const char*)As;
    const char* Bb = (const char*)Bs;

    for (int cq = 0; cq < 4; cq++) {
        const int ci0 = cq * 64;
        for (int tap = 0; tap < 9; tap++) {
            const int doff = ((tap / 3 - 1) * WP + (tap % 3 - 1)) * C_IN;
            const int woff = tap * (C_OUT * C_IN);
#pragma unroll
            for (int i = 0; i < 4; i++) {
                load_lds16(xbp + arow[i] + doff + ci0, ldsA + i * 2048);
                load_lds16(Wt + wrow[i] + woff + ci0, ldsB + i * 2048);
            }
            __syncthreads();
#pragma unroll
            for (int ks = 0; ks < 2; ks++) {
                bf16x8 af[4], bf[4];
#pragma unroll
                for (int mt = 0; mt < 4; mt++) af[mt] = *(const bf16x8*)(Ab + aoff[ks][mt]);
#pragma unroll
                for (int nt = 0; nt < 4; nt++) bf[nt] = *(const bf16x8*)(Bb + boff[ks][nt]);
#pragma unroll
                for (int mt = 0; mt < 4; mt++)
#pragma unroll
                    for (int nt = 0; nt < 4; nt++)
                        acc[mt][nt] = __builtin_amdgcn_mfma_f32_16x16x32_bf16(
                            af[mt], bf[nt], acc[mt][nt], 0, 0, 0);
            }
            __syncthreads();
        }
    }

    int coK[4], coD[4];
    float invK[4], addK[4], tscK[4];
#pragma unroll
    for (int nt = 0; nt < 4; nt++) {
        int j = waveN * 64 + nt * 16 + (lane & 15);
        coK[nt] = perm[b * C_OUT + j];
        coD[nt] = perm[b * C_OUT + K_ZERO + j];
        invK[nt] = bninv[coK[nt]];
        addK[nt] = bnadd[coK[nt]];
        tscK[nt] = cscale[b * K_ZERO + j];
    }
    const float4 z4 = make_float4(0.f, 0.f, 0.f, 0.f);
#pragma unroll
    for (int mt = 0; mt < 4; mt++) {
        int pl0 = tile * 128 + waveM * 64 + mt * 16 + (lane >> 4) * 4;
        if (pl0 < HW) {
#pragma unroll
            for (int nt = 0; nt < 4; nt++) {
                float inv = invK[nt], add = addK[nt], tsc = tscK[nt];
                float4 o;
                o.x = fmaxf(acc[mt][nt][0] * inv + add, 0.f) * tsc;
                o.y = fmaxf(acc[mt][nt][1] * inv + add, 0.f) * tsc;
                o.z = fmaxf(acc[mt][nt][2] * inv + add, 0.f) * tsc;
                o.w = fmaxf(acc[mt][nt][3] * inv + add, 0.f) * tsc;
                *(float4*)(out + (size_t)(b * C_OUT + coK[nt]) * HW + pl0) = o;
                *(float4*)(out + (size_t)(b * C_OUT + coD[nt]) * HW + pl0) = z4;
            }
        }
    }
}

// ---------------------------------------------------------------------------
extern "C" void kernel_launch(void* const* d_in, const int* in_sizes, int n_in,
                              void* d_out, int out_size, void* d_ws, size_t ws_size,
                              hipStream_t stream) {
    const float* x      = (const float*)d_in[0];
    const float* conv_w = (const float*)d_in[1];
    const float* gate_w = (const float*)d_in[2];
    const float* gate_b = (const float*)d_in[3];
    const float* bn_g   = (const float*)d_in[4];
    const float* bn_b   = (const float*)d_in[5];
    const float* bn_m   = (const float*)d_in[6];
    const float* bn_v   = (const float*)d_in[7];
    float* out = (float*)d_out;

    char* ws = (char*)d_ws;
    float*    s_part = (float*)(ws + 0);          // 32*56*256 f32 = 1835008 B
    ushort_t* perm   = (ushort_t*)(ws + 1835008); // 32*256 u16 (16 KB)
    float*    cscale = (float*)(ws + 1851392);    // 32*128 f  (16 KB)
    float*    bninv  = (float*)(ws + 1867776);    // 256 f
    float*    bnadd  = (float*)(ws + 1868800);    // 256 f
    ushort_t* Wt     = (ushort_t*)(ws + 1869824); // 589824 bf16 (1179648 B)
    ushort_t* xbp    = (ushort_t*)(ws + 3049472); // 32*58*58*256 bf16

    prep_kernel<<<NPX + 256, 256, 0, stream>>>(x, conv_w, bn_g, bn_b, bn_m, bn_v,
                                               Wt, bninv, bnadd, s_part, xbp);
    gate_kernel<<<32, 256, 0, stream>>>(s_part, gate_w, gate_b, perm, cscale);
    conv_kernel<<<dim3(25 * 32), 256, 0, stream>>>(xbp, Wt, bninv, bnadd, perm, cscale, out);
}

// Round 10
// 322.071 us; speedup vs baseline: 1.2422x; 1.0453x over previous
//
#include <hip/hip_runtime.h>
#include <hip/hip_bf16.h>
#include <cstdint>

typedef unsigned short ushort_t;
typedef unsigned int uint_t;
typedef __bf16 bf16x8 __attribute__((ext_vector_type(8)));
typedef float f32x4 __attribute__((ext_vector_type(4)));

#define B_SZ 32
#define C_IN 256
#define C_OUT 256
#define H_SZ 56
#define W_SZ 56
#define HW 3136          // 56*56
#define HP 58            // padded H (halo 1 each side)
#define WP 58            // padded W
#define BN_EPS 1e-5f
#define K_ZERO 128       // channels zeroed per batch; 128 survive
#define NPX 7168         // prep_x role blocks: 4 cit * 56 h * 32 b

__device__ __forceinline__ ushort_t f2bf(float f) {
    unsigned int u = __builtin_bit_cast(unsigned int, f);
    unsigned int r = (u + 0x7fffu + ((u >> 16) & 1u)) >> 16;
    return (ushort_t)r;
}

__device__ __forceinline__ void load_lds16(const void* gptr, void* ldsptr) {
    __builtin_amdgcn_global_load_lds(
        (const __attribute__((address_space(1))) unsigned int*)(uintptr_t)gptr,
        (__attribute__((address_space(3))) unsigned int*)(uintptr_t)ldsptr,
        16, 0, 0);
}

// ---------------------------------------------------------------------------
// Kernel 1 (MERGED prep): blocks [0,7168) do prep_x (x NCHW fp32 -> padded
// NHWC bf16 + per-(b,h) abs-mean partials, no atomics). Blocks [7168,7424)
// do prep_w (coalesced LDS-staged transpose to Wt[tap][co][ci] + BN consts).
// r9 attribution probe (idempotent work-doubling): T_prep ~= 17 us -- above
// its HBM roofline (x L3-resident); no further headroom worth pursuing.
// ---------------------------------------------------------------------------
__global__ __launch_bounds__(256) void prep_kernel(const float* __restrict__ x,
                                                   const float* __restrict__ w,
                                                   const float* __restrict__ gamma,
                                                   const float* __restrict__ beta,
                                                   const float* __restrict__ mean,
                                                   const float* __restrict__ var,
                                                   ushort_t* __restrict__ Wt,
                                                   float* __restrict__ bninv,
                                                   float* __restrict__ bnadd,
                                                   float* __restrict__ s_part,
                                                   ushort_t* __restrict__ xbp) {
    const int bx = blockIdx.x, t = threadIdx.x;
    __shared__ __align__(16) char smem[15616];   // max(tile 14592+red2 1024, wl 9216)

    if (bx >= NPX) {
        // ---- prep_w role: one block per co ----
        const int co = bx - NPX;
        float* wl = (float*)smem;   // 2304 floats
        const float4* src4 = (const float4*)(w + (size_t)co * 2304);
        for (int i = t; i < 576; i += 256) ((float4*)wl)[i] = src4[i];
        if (co == 32) {
            float inv = gamma[t] * rsqrtf(var[t] + BN_EPS);
            bninv[t] = inv;
            bnadd[t] = beta[t] - mean[t] * inv;
        }
        __syncthreads();
        for (int i = t; i < 2304; i += 256) {
            int tap = i >> 8, ci = i & 255;
            Wt[tap * (C_OUT * C_IN) + co * C_IN + ci] = f2bf(wl[ci * 9 + tap]);
        }
        return;
    }

    // ---- prep_x role: bx = (b*56+h)*4 + cit ----
    const int cit = bx & 3;
    const int hb = bx >> 2;        // b*56 + h
    const int h = hb % 56;
    const int b = hb / 56;
    float (*tile)[57] = (float (*)[57])smem;         // 64 x 57 fp32
    float* red2 = (float*)(smem + 14592);            // 256 fp32
    const float* src = x + ((size_t)(b * C_IN + cit * 64) * H_SZ + h) * W_SZ;
    for (int i = t; i < 64 * 14; i += 256) {
        int ci = i / 14, w4 = (i - ci * 14) * 4;
        float4 v = *(const float4*)(src + (size_t)ci * HW + w4);
        tile[ci][w4] = v.x; tile[ci][w4 + 1] = v.y;
        tile[ci][w4 + 2] = v.z; tile[ci][w4 + 3] = v.w;
    }
    __syncthreads();
    {
        int ci = t & 63, wg = t >> 6;
        float a = 0.f;
#pragma unroll
        for (int j = 0; j < 14; j++) a += fabsf(tile[ci][wg * 14 + j]);
        red2[t] = a;
    }
    __syncthreads();
    if (t < 64) {
        float tot = red2[t] + red2[t + 64] + red2[t + 128] + red2[t + 192];
        s_part[(size_t)hb * C_IN + cit * 64 + t] = tot * (1.0f / (float)HW);
    }
    const uint2 z2 = make_uint2(0u, 0u);
    for (int i = t; i < W_SZ * 8; i += 256) {
        int w_ = i >> 3, c8 = (i & 7) * 8;
        uint4 v;
        v.x = (uint_t)f2bf(tile[c8][w_])     | ((uint_t)f2bf(tile[c8 + 1][w_]) << 16);
        v.y = (uint_t)f2bf(tile[c8 + 2][w_]) | ((uint_t)f2bf(tile[c8 + 3][w_]) << 16);
        v.z = (uint_t)f2bf(tile[c8 + 4][w_]) | ((uint_t)f2bf(tile[c8 + 5][w_]) << 16);
        v.w = (uint_t)f2bf(tile[c8 + 6][w_]) | ((uint_t)f2bf(tile[c8 + 7][w_]) << 16);
        size_t dst = ((size_t)((b * HP + h + 1) * WP + (w_ + 1))) * C_IN + cit * 64 + c8;
        *(uint4*)&xbp[dst] = v;
    }
    if (t < 32) {
        int side = t >> 4, c4 = (t & 15) * 4;
        size_t dst = ((size_t)((b * HP + h + 1) * WP + side * 57)) * C_IN + cit * 64 + c4;
        *(uint2*)&xbp[dst] = z2;
    }
    if (h == 0 || h == 55) {
        int prow = (h == 0) ? 0 : 57;
        for (int i = t; i < 58 * 16; i += 256) {
            int w_ = i >> 4, c4 = (i & 15) * 4;
            size_t dst = ((size_t)((b * HP + prow) * WP + w_)) * C_IN + cit * 64 + c4;
            *(uint2*)&xbp[dst] = z2;
        }
    }
}

// ---------------------------------------------------------------------------
// Kernel 2: gate -> per-batch channel permutation + compacted scales.
// ---------------------------------------------------------------------------
__global__ __launch_bounds__(256) void gate_kernel(const float* __restrict__ s_part,
                                                   const float* __restrict__ gw,
                                                   const float* __restrict__ gb,
                                                   ushort_t* __restrict__ perm,
                                                   float* __restrict__ cscale) {
    const int b = blockIdx.x, t = threadIdx.x;
    __shared__ float sh_s[C_IN], sh_g[C_OUT], red[256];
    {
        const float* sp = s_part + (size_t)b * 56 * C_IN + t;
        float v = 0.f;
#pragma unroll 8
        for (int h = 0; h < 56; h++) v += sp[(size_t)h * C_IN];
        sh_s[t] = v;
    }
    __syncthreads();
    float acc = gb[t];
    const float4* s4 = (const float4*)sh_s;
    const float4* w4 = (const float4*)(gw + (size_t)t * C_IN);
    for (int ci = 0; ci < C_IN / 4; ci++) {
        float4 a = s4[ci], wv = w4[ci];
        acc += a.x * wv.x + a.y * wv.y + a.z * wv.z + a.w * wv.w;
    }
    float g = fmaxf(acc, 0.f);
    sh_g[t] = g;
    __syncthreads();
    int cnt = 0;
    for (int j = 0; j < C_OUT; j++) {
        float gj = sh_g[j];
        cnt += (gj < g) || (gj == g && j < t);
    }
    float tv = (cnt >= K_ZERO) ? g : 0.f;
    red[t] = tv;
    __syncthreads();
    for (int off = 128; off > 0; off >>= 1) {
        if (t < off) red[t] += red[t + off];
        __syncthreads();
    }
    if (cnt >= K_ZERO) {
        int pos = cnt - K_ZERO;
        perm[b * C_OUT + pos] = (ushort_t)t;
        cscale[b * K_ZERO + pos] = tv * ((float)C_OUT / red[0]);
    } else {
        perm[b * C_OUT + K_ZERO + cnt] = (ushort_t)t;
    }
}

// ---------------------------------------------------------------------------
// Kernel 3: implicit-GEMM conv + BN + ReLU over SURVIVING channels only.
// VERBATIM r2/r6/r7/r9-verified version (99 us, FETCH 35 MB, MfmaUtil 25%):
//  - cq OUTER / tap INNER (L2 working-set partition by 4)
//  - per-tap A staging via async global_load_lds DMA, row-keyed XOR swizzle
//  - chunked XCD swizzle (800%8==0 bijective)
// Refuted alternatives: A-window tap-reuse (r3/r4, +35 us), B-in-registers
// (r8, +85 us: lane-gather + vmcnt serialization beats no-LDS win).
// ---------------------------------------------------------------------------
__global__ __launch_bounds__(256, 3) void conv_kernel(const ushort_t* __restrict__ xbp,
                                                      const ushort_t* __restrict__ Wt,
                                                      const float* __restrict__ bninv,
                                                      const float* __restrict__ bnadd,
                                                      const ushort_t* __restrict__ perm,
                                                      const float* __restrict__ cscale,
                                                      float* __restrict__ out) {
    __shared__ __align__(16) ushort_t As[128 * 64];  // 16 KB
    __shared__ __align__(16) ushort_t Bs[128 * 64];  // 16 KB
    const int t = threadIdx.x;
    const int bxr = blockIdx.x;
    const int L = (bxr & 7) * 100 + (bxr >> 3);
    const int b = L / 25;          // 0..31, 4 consecutive batches per XCD
    const int tile = L - b * 25;   // 0..24 p-tiles within batch
    const int lane = t & 63;
    const int wv = t >> 6;
    const int waveM = wv >> 1, waveN = wv & 1;

    const int srow = t >> 3;
    const int gxor8 = ((t & 7) ^ (srow & 7)) * 8;
    int arow[4], wrow[4];
#pragma unroll
    for (int i = 0; i < 4; i++) {
        int pl = tile * 128 + i * 32 + srow;
        pl = pl < HW ? pl : HW - 1;          // clamp tail tile inside batch
        int hh = pl / W_SZ, ww = pl - hh * W_SZ;
        arow[i] = ((b * HP + hh + 1) * WP + (ww + 1)) * C_IN + gxor8;
        int co = perm[b * C_OUT + i * 32 + srow];  // surviving channel gather
        wrow[i] = co * C_IN + gxor8;
    }
    ushort_t* ldsA = As + t * 8;
    ushort_t* ldsB = Bs + t * 8;

    int aoff[2][4], boff[2][4];
#pragma unroll
    for (int ks = 0; ks < 2; ks++) {
        int c = (lane >> 4) + ks * 4;
#pragma unroll
        for (int mt = 0; mt < 4; mt++) {
            int ra = waveM * 64 + mt * 16 + (lane & 15);
            aoff[ks][mt] = (ra * 8 + (c ^ (ra & 7))) * 16;
            int rb = waveN * 64 + mt * 16 + (lane & 15);
            boff[ks][mt] = (rb * 8 + (c ^ (rb & 7))) * 16;
        }
    }

    f32x4 acc[4][4];
#pragma unroll
    for (int i = 0; i < 4; i++)
#pragma unroll
        for (int j = 0; j < 4; j++) acc[i][j] = (f32x4){0.f, 0.f, 0.f, 0.f};

    const char* Ab = (const char*)As;
    const char* Bb = (const char*)Bs;

    for (int cq = 0; cq < 4; cq++) {
        const int ci0 = cq * 64;
        for (int tap = 0; tap < 9; tap++) {
            const int doff = ((tap / 3 - 1) * WP + (tap % 3 - 1)) * C_IN;
            const int woff = tap * (C_OUT * C_IN);
#pragma unroll
            for (int i = 0; i < 4; i++) {
                load_lds16(xbp + arow[i] + doff + ci0, ldsA + i * 2048);
                load_lds16(Wt + wrow[i] + woff + ci0, ldsB + i * 2048);
            }
            __syncthreads();
#pragma unroll
            for (int ks = 0; ks < 2; ks++) {
                bf16x8 af[4], bf[4];
#pragma unroll
                for (int mt = 0; mt < 4; mt++) af[mt] = *(const bf16x8*)(Ab + aoff[ks][mt]);
#pragma unroll
                for (int nt = 0; nt < 4; nt++) bf[nt] = *(const bf16x8*)(Bb + boff[ks][nt]);
#pragma unroll
                for (int mt = 0; mt < 4; mt++)
#pragma unroll
                    for (int nt = 0; nt < 4; nt++)
                        acc[mt][nt] = __builtin_amdgcn_mfma_f32_16x16x32_bf16(
                            af[mt], bf[nt], acc[mt][nt], 0, 0, 0);
            }
            __syncthreads();
        }
    }

    int coK[4], coD[4];
    float invK[4], addK[4], tscK[4];
#pragma unroll
    for (int nt = 0; nt < 4; nt++) {
        int j = waveN * 64 + nt * 16 + (lane & 15);
        coK[nt] = perm[b * C_OUT + j];
        coD[nt] = perm[b * C_OUT + K_ZERO + j];
        invK[nt] = bninv[coK[nt]];
        addK[nt] = bnadd[coK[nt]];
        tscK[nt] = cscale[b * K_ZERO + j];
    }
    const float4 z4 = make_float4(0.f, 0.f, 0.f, 0.f);
#pragma unroll
    for (int mt = 0; mt < 4; mt++) {
        int pl0 = tile * 128 + waveM * 64 + mt * 16 + (lane >> 4) * 4;
        if (pl0 < HW) {
#pragma unroll
            for (int nt = 0; nt < 4; nt++) {
                float inv = invK[nt], add = addK[nt], tsc = tscK[nt];
                float4 o;
                o.x = fmaxf(acc[mt][nt][0] * inv + add, 0.f) * tsc;
                o.y = fmaxf(acc[mt][nt][1] * inv + add, 0.f) * tsc;
                o.z = fmaxf(acc[mt][nt][2] * inv + add, 0.f) * tsc;
                o.w = fmaxf(acc[mt][nt][3] * inv + add, 0.f) * tsc;
                *(float4*)(out + (size_t)(b * C_OUT + coK[nt]) * HW + pl0) = o;
                *(float4*)(out + (size_t)(b * C_OUT + coD[nt]) * HW + pl0) = z4;
            }
        }
    }
}

// ---------------------------------------------------------------------------
extern "C" void kernel_launch(void* const* d_in, const int* in_sizes, int n_in,
                              void* d_out, int out_size, void* d_ws, size_t ws_size,
                              hipStream_t stream) {
    const float* x      = (const float*)d_in[0];
    const float* conv_w = (const float*)d_in[1];
    const float* gate_w = (const float*)d_in[2];
    const float* gate_b = (const float*)d_in[3];
    const float* bn_g   = (const float*)d_in[4];
    const float* bn_b   = (const float*)d_in[5];
    const float* bn_m   = (const float*)d_in[6];
    const float* bn_v   = (const float*)d_in[7];
    float* out = (float*)d_out;

    char* ws = (char*)d_ws;
    float*    s_part = (float*)(ws + 0);          // 32*56*256 f32 = 1835008 B
    ushort_t* perm   = (ushort_t*)(ws + 1835008); // 32*256 u16 (16 KB)
    float*    cscale = (float*)(ws + 1851392);    // 32*128 f  (16 KB)
    float*    bninv  = (float*)(ws + 1867776);    // 256 f
    float*    bnadd  = (float*)(ws + 1868800);    // 256 f
    ushort_t* Wt     = (ushort_t*)(ws + 1869824); // 589824 bf16 (1179648 B)
    ushort_t* xbp    = (ushort_t*)(ws + 3049472); // 32*58*58*256 bf16

    prep_kernel<<<NPX + 256, 256, 0, stream>>>(x, conv_w, bn_g, bn_b, bn_m, bn_v,
                                               Wt, bninv, bnadd, s_part, xbp);
    gate_kernel<<<32, 256, 0, stream>>>(s_part, gate_w, gate_b, perm, cscale);
    conv_kernel<<<dim3(25 * 32), 256, 0, stream>>>(xbp, Wt, bninv, bnadd, perm, cscale, out);
}